// Round 2
// baseline (186.459 us; speedup 1.0000x reference)
//
#include <hip/hip_runtime.h>

#define BB 32
#define LL 4096
#define DD 1024
#define ROWS 128
#define K2_TILE 128
#define K3_TILE 128

static __device__ __forceinline__ int imax(int a, int b) { return a > b ? a : b; }
static __device__ __forceinline__ int imin(int a, int b) { return a < b ? a : b; }

// K1: accumulate per-span sums into sums[B][3][D] via atomics.
// Spans tile [s1, e2]: seg0=[s1,e1], seg1=[e1+1,s2-1], seg2=[s2,e2].
__global__ __launch_bounds__(256) void k1_sums(const float* __restrict__ h,
                                               const int* __restrict__ sp1,
                                               const int* __restrict__ sp2,
                                               float* __restrict__ sums) {
    const int b = blockIdx.y;
    const int tid = threadIdx.x;
    const int s1 = sp1[2 * b];
    const int e1 = sp1[2 * b + 1];
    const int s2 = sp2[2 * b];
    const int e2 = sp2[2 * b + 1];
    const int lo = s1;
    const int hi = e2 + 1;

    const int row0 = blockIdx.x * ROWS;
    const int rbeg = imax(row0, lo);
    const int rend = imin(row0 + ROWS, hi);
    if (rbeg >= rend) return;

    float4 a0 = make_float4(0.f, 0.f, 0.f, 0.f);
    float4 a1 = make_float4(0.f, 0.f, 0.f, 0.f);
    float4 a2 = make_float4(0.f, 0.f, 0.f, 0.f);

    const float* hb = h + (size_t)b * LL * DD + (size_t)tid * 4;
    for (int l = rbeg; l < rend; ++l) {
        float4 v = *(const float4*)(hb + (size_t)l * DD);
        if (l <= e1) {            // span1
            a0.x += v.x; a0.y += v.y; a0.z += v.z; a0.w += v.w;
        } else if (l < s2) {      // context
            a1.x += v.x; a1.y += v.y; a1.z += v.z; a1.w += v.w;
        } else {                  // span2
            a2.x += v.x; a2.y += v.y; a2.z += v.z; a2.w += v.w;
        }
    }

    float* dst = sums + (size_t)b * 3 * DD + (size_t)tid * 4;
    if (rbeg <= e1) {  // seg0 touched
        atomicAdd(dst + 0, a0.x); atomicAdd(dst + 1, a0.y);
        atomicAdd(dst + 2, a0.z); atomicAdd(dst + 3, a0.w);
    }
    if (imax(rbeg, e1 + 1) < imin(rend, s2)) {  // seg1 touched
        atomicAdd(dst + DD + 0, a1.x); atomicAdd(dst + DD + 1, a1.y);
        atomicAdd(dst + DD + 2, a1.z); atomicAdd(dst + DD + 3, a1.w);
    }
    if (imax(rbeg, s2) < rend) {  // seg2 touched
        atomicAdd(dst + 2 * DD + 0, a2.x); atomicAdd(dst + 2 * DD + 1, a2.y);
        atomicAdd(dst + 2 * DD + 2, a2.z); atomicAdd(dst + 2 * DD + 3, a2.w);
    }
}

// K1b: combined[b][k] = sums[b][seg][d] / cnt_seg  (k = seg*D + d)
__global__ __launch_bounds__(256) void k1b_comb(const float* __restrict__ sums,
                                                const int* __restrict__ sp1,
                                                const int* __restrict__ sp2,
                                                float* __restrict__ comb) {
    const int b = blockIdx.x;
    const int s1 = sp1[2 * b];
    const int e1 = sp1[2 * b + 1];
    const int s2 = sp2[2 * b];
    const int e2 = sp2[2 * b + 1];
    const float ic0 = 1.0f / (float)imax(e1 + 1 - s1, 1);
    const float ic1 = 1.0f / (float)imax(s2 - (e1 + 1), 1);
    const float ic2 = 1.0f / (float)imax(e2 + 1 - s2, 1);
    for (int i = threadIdx.x; i < 3 * DD; i += 256) {
        const int seg = i / DD;
        const float ic = (seg == 0) ? ic0 : (seg == 1) ? ic1 : ic2;
        comb[(size_t)b * 3 * DD + i] = sums[(size_t)b * 3 * DD + i] * ic;
    }
}

// K2: hmid_raw[b][j] += sum over k-tile of combined[b][k] * W1[k][j]
// grid (D/256, 3D/K2_TILE); thread owns column j, 32 per-batch accumulators.
__global__ __launch_bounds__(256) void k2_gemm1(const float* __restrict__ comb,
                                                const float* __restrict__ W1,
                                                float* __restrict__ hmid) {
    __shared__ float cl[K2_TILE * BB];  // [kk][b], 16 KiB
    const int j = blockIdx.x * 256 + threadIdx.x;
    const int k0 = blockIdx.y * K2_TILE;

    for (int i = threadIdx.x; i < K2_TILE * BB; i += 256) {
        const int kk = i / BB;
        const int b = i % BB;
        cl[i] = comb[(size_t)b * (3 * DD) + (k0 + kk)];
    }
    __syncthreads();

    float acc[BB];
#pragma unroll
    for (int b = 0; b < BB; ++b) acc[b] = 0.f;

    const float* w = W1 + (size_t)k0 * DD + j;
    for (int kk = 0; kk < K2_TILE; ++kk) {
        const float wv = w[(size_t)kk * DD];
        const float4* c4 = (const float4*)(cl + kk * BB);
#pragma unroll
        for (int q = 0; q < BB / 4; ++q) {
            float4 c = c4[q];
            acc[4 * q + 0] = fmaf(c.x, wv, acc[4 * q + 0]);
            acc[4 * q + 1] = fmaf(c.y, wv, acc[4 * q + 1]);
            acc[4 * q + 2] = fmaf(c.z, wv, acc[4 * q + 2]);
            acc[4 * q + 3] = fmaf(c.w, wv, acc[4 * q + 3]);
        }
    }
#pragma unroll
    for (int b = 0; b < BB; ++b) atomicAdd(&hmid[(size_t)b * DD + j], acc[b]);
}

// K3: out[b][j] += sum over k-tile of relu(hmid[b][k]+b1[k]) * W2[k][j]  (+ b2 once)
__global__ __launch_bounds__(256) void k3_gemm2(const float* __restrict__ hmid,
                                                const float* __restrict__ b1,
                                                const float* __restrict__ W2,
                                                const float* __restrict__ b2,
                                                float* __restrict__ out) {
    __shared__ float al[K3_TILE * BB];  // [kk][b]
    const int j = blockIdx.x * 256 + threadIdx.x;
    const int k0 = blockIdx.y * K3_TILE;

    for (int i = threadIdx.x; i < K3_TILE * BB; i += 256) {
        const int kk = i / BB;
        const int b = i % BB;
        const float v = hmid[(size_t)b * DD + (k0 + kk)] + b1[k0 + kk];
        al[i] = fmaxf(v, 0.f);
    }
    __syncthreads();

    float acc[BB];
    const float bias = (blockIdx.y == 0) ? b2[j] : 0.f;
#pragma unroll
    for (int b = 0; b < BB; ++b) acc[b] = bias;

    const float* w = W2 + (size_t)k0 * DD + j;
    for (int kk = 0; kk < K3_TILE; ++kk) {
        const float wv = w[(size_t)kk * DD];
        const float4* c4 = (const float4*)(al + kk * BB);
#pragma unroll
        for (int q = 0; q < BB / 4; ++q) {
            float4 c = c4[q];
            acc[4 * q + 0] = fmaf(c.x, wv, acc[4 * q + 0]);
            acc[4 * q + 1] = fmaf(c.y, wv, acc[4 * q + 1]);
            acc[4 * q + 2] = fmaf(c.z, wv, acc[4 * q + 2]);
            acc[4 * q + 3] = fmaf(c.w, wv, acc[4 * q + 3]);
        }
    }
#pragma unroll
    for (int b = 0; b < BB; ++b) atomicAdd(&out[(size_t)b * DD + j], acc[b]);
}

extern "C" void kernel_launch(void* const* d_in, const int* in_sizes, int n_in,
                              void* d_out, int out_size, void* d_ws, size_t ws_size,
                              hipStream_t stream) {
    const float* h = (const float*)d_in[0];
    const int* sp1 = (const int*)d_in[1];
    const int* sp2 = (const int*)d_in[2];
    const float* W1 = (const float*)d_in[3];
    const float* b1 = (const float*)d_in[4];
    const float* W2 = (const float*)d_in[5];
    const float* b2 = (const float*)d_in[6];
    float* out = (float*)d_out;

    float* sums = (float*)d_ws;            // B*3*D floats = 384 KiB
    float* hmid = sums + BB * 3 * DD;      // B*D floats   = 128 KiB
    float* comb = hmid + BB * DD;          // B*3*D floats = 384 KiB

    // Zero the atomic-accumulated regions (sums + hmid) and d_out each call.
    hipMemsetAsync(d_ws, 0, (size_t)(BB * 3 * DD + BB * DD) * sizeof(float), stream);
    hipMemsetAsync(d_out, 0, (size_t)(BB * DD) * sizeof(float), stream);

    k1_sums<<<dim3(LL / ROWS, BB), 256, 0, stream>>>(h, sp1, sp2, sums);
    k1b_comb<<<BB, 256, 0, stream>>>(sums, sp1, sp2, comb);
    k2_gemm1<<<dim3(DD / 256, 3 * DD / K2_TILE), 256, 0, stream>>>(comb, W1, hmid);
    k3_gemm2<<<dim3(DD / 256, DD / K3_TILE), 256, 0, stream>>>(hmid, b1, W2, b2, out);
}

// Round 3
// 157.893 us; speedup vs baseline: 1.1809x; 1.1809x over previous
//
#include <hip/hip_runtime.h>

#define BB 32
#define LL 4096
#define DD 1024
#define ROWS 128
#define K2_TILE 128
#define K3_TILE 128

static __device__ __forceinline__ int imax(int a, int b) { return a > b ? a : b; }
static __device__ __forceinline__ int imin(int a, int b) { return a < b ? a : b; }

// K0: zero the atomic-accumulated regions: sums+hmid (contiguous in ws) and out.
// sums = BB*3*DD floats, hmid = BB*DD floats -> 131072 floats = 32768 float4.
// out  = BB*DD floats = 8192 float4.  grid = 160 blocks x 256 threads.
__global__ __launch_bounds__(256) void k0_zero(float* __restrict__ ws,
                                               float* __restrict__ out) {
    const int i = blockIdx.x * 256 + threadIdx.x;
    const float4 z = make_float4(0.f, 0.f, 0.f, 0.f);
    if (i < 32768) ((float4*)ws)[i] = z;
    else ((float4*)out)[i - 32768] = z;
}

// Branch-free row-range accumulate with 4-deep unroll (4 outstanding float4 loads).
static __device__ __forceinline__ void accum_rows(const float* __restrict__ hb,
                                                  int beg, int end, float4& acc) {
    float4 a0 = make_float4(0.f, 0.f, 0.f, 0.f);
    float4 a1 = make_float4(0.f, 0.f, 0.f, 0.f);
    float4 a2 = make_float4(0.f, 0.f, 0.f, 0.f);
    float4 a3 = make_float4(0.f, 0.f, 0.f, 0.f);
    int l = beg;
    for (; l + 4 <= end; l += 4) {
        float4 v0 = *(const float4*)(hb + (size_t)(l + 0) * DD);
        float4 v1 = *(const float4*)(hb + (size_t)(l + 1) * DD);
        float4 v2 = *(const float4*)(hb + (size_t)(l + 2) * DD);
        float4 v3 = *(const float4*)(hb + (size_t)(l + 3) * DD);
        a0.x += v0.x; a0.y += v0.y; a0.z += v0.z; a0.w += v0.w;
        a1.x += v1.x; a1.y += v1.y; a1.z += v1.z; a1.w += v1.w;
        a2.x += v2.x; a2.y += v2.y; a2.z += v2.z; a2.w += v2.w;
        a3.x += v3.x; a3.y += v3.y; a3.z += v3.z; a3.w += v3.w;
    }
    for (; l < end; ++l) {
        float4 v = *(const float4*)(hb + (size_t)l * DD);
        a0.x += v.x; a0.y += v.y; a0.z += v.z; a0.w += v.w;
    }
    acc.x = (a0.x + a1.x) + (a2.x + a3.x);
    acc.y = (a0.y + a1.y) + (a2.y + a3.y);
    acc.z = (a0.z + a1.z) + (a2.z + a3.z);
    acc.w = (a0.w + a1.w) + (a2.w + a3.w);
}

// K1: per-span sums into sums[B][3][D] via atomics.
// seg0=[s1,e1+1), seg1=[e1+1,s2), seg2=[s2,e2+1) — contiguous intervals.
__global__ __launch_bounds__(256) void k1_sums(const float* __restrict__ h,
                                               const int* __restrict__ sp1,
                                               const int* __restrict__ sp2,
                                               float* __restrict__ sums) {
    const int b = blockIdx.y;
    const int tid = threadIdx.x;
    const int s1 = sp1[2 * b];
    const int e1 = sp1[2 * b + 1];
    const int s2 = sp2[2 * b];
    const int e2 = sp2[2 * b + 1];

    const int row0 = blockIdx.x * ROWS;
    const int row1 = row0 + ROWS;
    if (row1 <= s1 || row0 > e2) return;

    const float* hb = h + (size_t)b * LL * DD + (size_t)tid * 4;
    float* dst = sums + (size_t)b * 3 * DD + (size_t)tid * 4;

    const int lo[3] = {s1, e1 + 1, s2};
    const int hi[3] = {e1 + 1, s2, e2 + 1};
#pragma unroll
    for (int seg = 0; seg < 3; ++seg) {
        const int beg = imax(row0, lo[seg]);
        const int end = imin(row1, hi[seg]);
        if (beg < end) {
            float4 a;
            accum_rows(hb, beg, end, a);
            float* d = dst + seg * DD;
            atomicAdd(d + 0, a.x); atomicAdd(d + 1, a.y);
            atomicAdd(d + 2, a.z); atomicAdd(d + 3, a.w);
        }
    }
}

// K1b: combined[b][k] = sums[b][seg][d] / cnt_seg  (k = seg*D + d)
__global__ __launch_bounds__(256) void k1b_comb(const float* __restrict__ sums,
                                                const int* __restrict__ sp1,
                                                const int* __restrict__ sp2,
                                                float* __restrict__ comb) {
    const int b = blockIdx.x;
    const int s1 = sp1[2 * b];
    const int e1 = sp1[2 * b + 1];
    const int s2 = sp2[2 * b];
    const int e2 = sp2[2 * b + 1];
    const float ic0 = 1.0f / (float)imax(e1 + 1 - s1, 1);
    const float ic1 = 1.0f / (float)imax(s2 - (e1 + 1), 1);
    const float ic2 = 1.0f / (float)imax(e2 + 1 - s2, 1);
    for (int i = threadIdx.x; i < 3 * DD; i += 256) {
        const int seg = i / DD;
        const float ic = (seg == 0) ? ic0 : (seg == 1) ? ic1 : ic2;
        comb[(size_t)b * 3 * DD + i] = sums[(size_t)b * 3 * DD + i] * ic;
    }
}

// K2: hmid[b][j] += sum over k-tile of combined[b][k] * W1[k][j]
__global__ __launch_bounds__(256) void k2_gemm1(const float* __restrict__ comb,
                                                const float* __restrict__ W1,
                                                float* __restrict__ hmid) {
    __shared__ float cl[K2_TILE * BB];  // [kk][b], 16 KiB
    const int j = blockIdx.x * 256 + threadIdx.x;
    const int k0 = blockIdx.y * K2_TILE;

    for (int i = threadIdx.x; i < K2_TILE * BB; i += 256) {
        const int kk = i / BB;
        const int b = i % BB;
        cl[i] = comb[(size_t)b * (3 * DD) + (k0 + kk)];
    }
    __syncthreads();

    float acc[BB];
#pragma unroll
    for (int b = 0; b < BB; ++b) acc[b] = 0.f;

    const float* w = W1 + (size_t)k0 * DD + j;
    for (int kk = 0; kk < K2_TILE; ++kk) {
        const float wv = w[(size_t)kk * DD];
        const float4* c4 = (const float4*)(cl + kk * BB);
#pragma unroll
        for (int q = 0; q < BB / 4; ++q) {
            float4 c = c4[q];
            acc[4 * q + 0] = fmaf(c.x, wv, acc[4 * q + 0]);
            acc[4 * q + 1] = fmaf(c.y, wv, acc[4 * q + 1]);
            acc[4 * q + 2] = fmaf(c.z, wv, acc[4 * q + 2]);
            acc[4 * q + 3] = fmaf(c.w, wv, acc[4 * q + 3]);
        }
    }
#pragma unroll
    for (int b = 0; b < BB; ++b) atomicAdd(&hmid[(size_t)b * DD + j], acc[b]);
}

// K3: out[b][j] += sum over k-tile of relu(hmid[b][k]+b1[k]) * W2[k][j]  (+ b2 once)
__global__ __launch_bounds__(256) void k3_gemm2(const float* __restrict__ hmid,
                                                const float* __restrict__ b1,
                                                const float* __restrict__ W2,
                                                const float* __restrict__ b2,
                                                float* __restrict__ out) {
    __shared__ float al[K3_TILE * BB];  // [kk][b]
    const int j = blockIdx.x * 256 + threadIdx.x;
    const int k0 = blockIdx.y * K3_TILE;

    for (int i = threadIdx.x; i < K3_TILE * BB; i += 256) {
        const int kk = i / BB;
        const int b = i % BB;
        const float v = hmid[(size_t)b * DD + (k0 + kk)] + b1[k0 + kk];
        al[i] = fmaxf(v, 0.f);
    }
    __syncthreads();

    float acc[BB];
    const float bias = (blockIdx.y == 0) ? b2[j] : 0.f;
#pragma unroll
    for (int b = 0; b < BB; ++b) acc[b] = bias;

    const float* w = W2 + (size_t)k0 * DD + j;
    for (int kk = 0; kk < K3_TILE; ++kk) {
        const float wv = w[(size_t)kk * DD];
        const float4* c4 = (const float4*)(al + kk * BB);
#pragma unroll
        for (int q = 0; q < BB / 4; ++q) {
            float4 c = c4[q];
            acc[4 * q + 0] = fmaf(c.x, wv, acc[4 * q + 0]);
            acc[4 * q + 1] = fmaf(c.y, wv, acc[4 * q + 1]);
            acc[4 * q + 2] = fmaf(c.z, wv, acc[4 * q + 2]);
            acc[4 * q + 3] = fmaf(c.w, wv, acc[4 * q + 3]);
        }
    }
#pragma unroll
    for (int b = 0; b < BB; ++b) atomicAdd(&out[(size_t)b * DD + j], acc[b]);
}

extern "C" void kernel_launch(void* const* d_in, const int* in_sizes, int n_in,
                              void* d_out, int out_size, void* d_ws, size_t ws_size,
                              hipStream_t stream) {
    const float* h = (const float*)d_in[0];
    const int* sp1 = (const int*)d_in[1];
    const int* sp2 = (const int*)d_in[2];
    const float* W1 = (const float*)d_in[3];
    const float* b1 = (const float*)d_in[4];
    const float* W2 = (const float*)d_in[5];
    const float* b2 = (const float*)d_in[6];
    float* out = (float*)d_out;

    float* sums = (float*)d_ws;            // B*3*D floats = 384 KiB
    float* hmid = sums + BB * 3 * DD;      // B*D floats   = 128 KiB (contiguous after sums)
    float* comb = hmid + BB * DD;          // B*3*D floats = 384 KiB

    k0_zero<<<160, 256, 0, stream>>>((float*)d_ws, out);
    k1_sums<<<dim3(LL / ROWS, BB), 256, 0, stream>>>(h, sp1, sp2, sums);
    k1b_comb<<<BB, 256, 0, stream>>>(sums, sp1, sp2, comb);
    k2_gemm1<<<dim3(DD / 256, 3 * DD / K2_TILE), 256, 0, stream>>>(comb, W1, hmid);
    k3_gemm2<<<dim3(DD / 256, DD / K3_TILE), 256, 0, stream>>>(hmid, b1, W2, b2, out);
}

// Round 4
// 111.202 us; speedup vs baseline: 1.6768x; 1.4199x over previous
//
#include <hip/hip_runtime.h>

#define BB 32
#define LL 4096
#define DD 1024
#define CH 16      // rows per work chunk in k1
#define G1 1024    // k1 grid
#define K2_TILE 64
#define K3_TILE 32

static __device__ __forceinline__ int imax(int a, int b) { return a > b ? a : b; }
static __device__ __forceinline__ int imin(int a, int b) { return a < b ? a : b; }

// K0: zero sums (BB*3*DD) + hmid (BB*DD) in ws, and out.
// 131072 ws floats = 32768 float4; out 8192 float4 -> 160 blocks x 256.
__global__ __launch_bounds__(256) void k0_zero(float* __restrict__ ws,
                                               float* __restrict__ out) {
    const int i = blockIdx.x * 256 + threadIdx.x;
    const float4 z = make_float4(0.f, 0.f, 0.f, 0.f);
    if (i < 32768) ((float4*)ws)[i] = z;
    else ((float4*)out)[i - 32768] = z;
}

// Add rows [beg,end) into acc, 4-deep unrolled (4 outstanding float4 loads).
static __device__ __forceinline__ void accum_rows_add(const float* __restrict__ hb,
                                                      int beg, int end, float4& acc) {
    float4 a0 = make_float4(0.f, 0.f, 0.f, 0.f);
    float4 a1 = make_float4(0.f, 0.f, 0.f, 0.f);
    float4 a2 = make_float4(0.f, 0.f, 0.f, 0.f);
    float4 a3 = make_float4(0.f, 0.f, 0.f, 0.f);
    int l = beg;
    for (; l + 4 <= end; l += 4) {
        float4 v0 = *(const float4*)(hb + (size_t)(l + 0) * DD);
        float4 v1 = *(const float4*)(hb + (size_t)(l + 1) * DD);
        float4 v2 = *(const float4*)(hb + (size_t)(l + 2) * DD);
        float4 v3 = *(const float4*)(hb + (size_t)(l + 3) * DD);
        a0.x += v0.x; a0.y += v0.y; a0.z += v0.z; a0.w += v0.w;
        a1.x += v1.x; a1.y += v1.y; a1.z += v1.z; a1.w += v1.w;
        a2.x += v2.x; a2.y += v2.y; a2.z += v2.z; a2.w += v2.w;
        a3.x += v3.x; a3.y += v3.y; a3.z += v3.z; a3.w += v3.w;
    }
    for (; l < end; ++l) {
        float4 v = *(const float4*)(hb + (size_t)l * DD);
        a0.x += v.x; a0.y += v.y; a0.z += v.z; a0.w += v.w;
    }
    acc.x += (a0.x + a1.x) + (a2.x + a3.x);
    acc.y += (a0.y + a1.y) + (a2.y + a3.y);
    acc.z += (a0.z + a1.z) + (a2.z + a3.z);
    acc.w += (a0.w + a1.w) + (a2.w + a3.w);
}

// K1: balanced flat decomposition. Work = equal CH-row chunks over each batch's
// span [s1,e2]; each block takes a CONTIGUOUS range of chunks (q = ceil(NC/G)).
// (batch,seg) keys are monotone within a block -> register accum, flush on change.
__global__ __launch_bounds__(256) void k1_sums(const float* __restrict__ h,
                                               const int* __restrict__ sp1,
                                               const int* __restrict__ sp2,
                                               float* __restrict__ sums) {
    const int tid = threadIdx.x;

    int NC = 0;
#pragma unroll
    for (int b = 0; b < BB; ++b) {
        const int len = sp2[2 * b + 1] - sp1[2 * b] + 1;
        NC += (len + CH - 1) / CH;
    }
    const int q = (NC + (int)gridDim.x - 1) / (int)gridDim.x;
    const int c0 = blockIdx.x * q;
    const int c1 = imin(c0 + q, NC);
    if (c0 >= c1) return;

    // locate batch containing chunk c0
    int b = 0, base = 0, s1, e1, s2, e2, ncb;
    for (;; ++b) {
        s1 = sp1[2 * b]; e1 = sp1[2 * b + 1];
        s2 = sp2[2 * b]; e2 = sp2[2 * b + 1];
        ncb = (e2 - s1 + 1 + CH - 1) / CH;
        if (c0 < base + ncb) break;
        base += ncb;
    }
    const float* hb = h + (size_t)b * LL * DD + (size_t)tid * 4;
    float* dstb = sums + (size_t)b * 3 * DD + (size_t)tid * 4;

    float* kdst = nullptr;
    float4 acc = make_float4(0.f, 0.f, 0.f, 0.f);
    for (int c = c0; c < c1; ++c) {
        if (c >= base + ncb) {  // advance to next batch
            base += ncb; ++b;
            s1 = sp1[2 * b]; e1 = sp1[2 * b + 1];
            s2 = sp2[2 * b]; e2 = sp2[2 * b + 1];
            ncb = (e2 - s1 + 1 + CH - 1) / CH;
            hb = h + (size_t)b * LL * DD + (size_t)tid * 4;
            dstb = sums + (size_t)b * 3 * DD + (size_t)tid * 4;
        }
        const int beg = s1 + (c - base) * CH;
        const int end = imin(beg + CH, e2 + 1);
        const int lo[3] = {beg, imax(beg, e1 + 1), imax(beg, s2)};
        const int hi[3] = {imin(end, e1 + 1), imin(end, s2), end};
#pragma unroll
        for (int sgi = 0; sgi < 3; ++sgi) {
            if (lo[sgi] < hi[sgi]) {
                float* d = dstb + sgi * DD;
                if (d != kdst) {
                    if (kdst) {
                        atomicAdd(kdst + 0, acc.x); atomicAdd(kdst + 1, acc.y);
                        atomicAdd(kdst + 2, acc.z); atomicAdd(kdst + 3, acc.w);
                    }
                    kdst = d;
                    acc = make_float4(0.f, 0.f, 0.f, 0.f);
                }
                accum_rows_add(hb, lo[sgi], hi[sgi], acc);
            }
        }
    }
    if (kdst) {
        atomicAdd(kdst + 0, acc.x); atomicAdd(kdst + 1, acc.y);
        atomicAdd(kdst + 2, acc.z); atomicAdd(kdst + 3, acc.w);
    }
}

// K2 (k1b folded in): hmid[b][j] += sum_{k in tile} (sums[b][k]*ic) * W1[k][j]
// Tile lies in one seg (K2_TILE divides DD).
__global__ __launch_bounds__(256) void k2_gemm1(const float* __restrict__ sums,
                                                const int* __restrict__ sp1,
                                                const int* __restrict__ sp2,
                                                const float* __restrict__ W1,
                                                float* __restrict__ hmid) {
    __shared__ float cl[K2_TILE * BB];  // [kk][b]
    __shared__ float icl[BB];
    const int tid = threadIdx.x;
    const int j = blockIdx.x * 256 + tid;
    const int k0 = blockIdx.y * K2_TILE;
    const int seg = k0 / DD;

    if (tid < BB) {
        const int b = tid;
        const int s1 = sp1[2 * b], e1 = sp1[2 * b + 1];
        const int s2 = sp2[2 * b], e2 = sp2[2 * b + 1];
        const int cnt = (seg == 0) ? (e1 + 1 - s1) : (seg == 1) ? (s2 - e1 - 1) : (e2 + 1 - s2);
        icl[b] = 1.0f / (float)imax(cnt, 1);
    }
    __syncthreads();
    for (int i = tid; i < K2_TILE * BB; i += 256) {
        const int kk = i / BB;
        const int b = i % BB;
        cl[i] = sums[(size_t)b * (3 * DD) + (k0 + kk)] * icl[b];
    }
    __syncthreads();

    float acc[BB];
#pragma unroll
    for (int b = 0; b < BB; ++b) acc[b] = 0.f;

    const float* w = W1 + (size_t)k0 * DD + j;
    for (int kk = 0; kk < K2_TILE; ++kk) {
        const float wv = w[(size_t)kk * DD];
        const float4* c4 = (const float4*)(cl + kk * BB);
#pragma unroll
        for (int qq = 0; qq < BB / 4; ++qq) {
            float4 c = c4[qq];
            acc[4 * qq + 0] = fmaf(c.x, wv, acc[4 * qq + 0]);
            acc[4 * qq + 1] = fmaf(c.y, wv, acc[4 * qq + 1]);
            acc[4 * qq + 2] = fmaf(c.z, wv, acc[4 * qq + 2]);
            acc[4 * qq + 3] = fmaf(c.w, wv, acc[4 * qq + 3]);
        }
    }
#pragma unroll
    for (int b = 0; b < BB; ++b) atomicAdd(&hmid[(size_t)b * DD + j], acc[b]);
}

// K3: out[b][j] += sum_{k in tile} relu(hmid[b][k]+b1[k]) * W2[k][j]  (+ b2 once)
__global__ __launch_bounds__(256) void k3_gemm2(const float* __restrict__ hmid,
                                                const float* __restrict__ b1,
                                                const float* __restrict__ W2,
                                                const float* __restrict__ b2,
                                                float* __restrict__ out) {
    __shared__ float al[K3_TILE * BB];  // [kk][b]
    const int tid = threadIdx.x;
    const int j = blockIdx.x * 256 + tid;
    const int k0 = blockIdx.y * K3_TILE;

    for (int i = tid; i < K3_TILE * BB; i += 256) {
        const int kk = i / BB;
        const int b = i % BB;
        const float v = hmid[(size_t)b * DD + (k0 + kk)] + b1[k0 + kk];
        al[i] = fmaxf(v, 0.f);
    }
    __syncthreads();

    float acc[BB];
    const float bias = (blockIdx.y == 0) ? b2[j] : 0.f;
#pragma unroll
    for (int b = 0; b < BB; ++b) acc[b] = bias;

    const float* w = W2 + (size_t)k0 * DD + j;
    for (int kk = 0; kk < K3_TILE; ++kk) {
        const float wv = w[(size_t)kk * DD];
        const float4* c4 = (const float4*)(al + kk * BB);
#pragma unroll
        for (int qq = 0; qq < BB / 4; ++qq) {
            float4 c = c4[qq];
            acc[4 * qq + 0] = fmaf(c.x, wv, acc[4 * qq + 0]);
            acc[4 * qq + 1] = fmaf(c.y, wv, acc[4 * qq + 1]);
            acc[4 * qq + 2] = fmaf(c.z, wv, acc[4 * qq + 2]);
            acc[4 * qq + 3] = fmaf(c.w, wv, acc[4 * qq + 3]);
        }
    }
#pragma unroll
    for (int b = 0; b < BB; ++b) atomicAdd(&out[(size_t)b * DD + j], acc[b]);
}

extern "C" void kernel_launch(void* const* d_in, const int* in_sizes, int n_in,
                              void* d_out, int out_size, void* d_ws, size_t ws_size,
                              hipStream_t stream) {
    const float* h = (const float*)d_in[0];
    const int* sp1 = (const int*)d_in[1];
    const int* sp2 = (const int*)d_in[2];
    const float* W1 = (const float*)d_in[3];
    const float* b1 = (const float*)d_in[4];
    const float* W2 = (const float*)d_in[5];
    const float* b2 = (const float*)d_in[6];
    float* out = (float*)d_out;

    float* sums = (float*)d_ws;            // B*3*D floats
    float* hmid = sums + BB * 3 * DD;      // B*D floats (contiguous after sums)

    k0_zero<<<160, 256, 0, stream>>>((float*)d_ws, out);
    k1_sums<<<G1, 256, 0, stream>>>(h, sp1, sp2, sums);
    k2_gemm1<<<dim3(DD / 256, 3 * DD / K2_TILE), 256, 0, stream>>>(sums, sp1, sp2, W1, hmid);
    k3_gemm2<<<dim3(DD / 256, DD / K3_TILE), 256, 0, stream>>>(hmid, b1, W2, b2, out);
}